// Round 1
// baseline (1795.934 us; speedup 1.0000x reference)
//
#include <hip/hip_runtime.h>
#include <math.h>

#define NN 20000
#define NE 160000
#define DH 128

__device__ __forceinline__ float wave_sum(float v) {
#pragma unroll
  for (int off = 1; off < 64; off <<= 1) v += __shfl_xor(v, off, 64);
  return v;
}

// ---------------- CSR build ----------------
__global__ void count_kernel(const int* __restrict__ dst, int* __restrict__ deg, int n) {
  int i = blockIdx.x * blockDim.x + threadIdx.x;
  if (i < n) atomicAdd(&deg[dst[i]], 1);
}

__global__ void scan_phase1(const int* __restrict__ deg, int* __restrict__ rowstart,
                            int* __restrict__ bs, int n) {
  int lane = threadIdx.x;
  int i = blockIdx.x * 64 + lane;
  int v = (i < n) ? deg[i] : 0;
#pragma unroll
  for (int off = 1; off < 64; off <<= 1) {
    int u = __shfl_up(v, off, 64);
    if (lane >= off) v += u;
  }
  if (i < n) rowstart[i + 1] = v;  // block-local inclusive
  if (lane == 63) bs[blockIdx.x] = v;
}

__global__ void scan_phase2(int* __restrict__ bs, int nb) {
  int lane = threadIdx.x;
  int carry = 0;
  for (int base = 0; base < nb; base += 64) {
    int i = base + lane;
    int v = (i < nb) ? bs[i] : 0;
    int orig = v;
#pragma unroll
    for (int off = 1; off < 64; off <<= 1) {
      int u = __shfl_up(v, off, 64);
      if (lane >= off) v += u;
    }
    if (i < nb) bs[i] = carry + v - orig;  // exclusive
    carry += __shfl(v, 63, 64);
  }
}

__global__ void scan_phase3(int* __restrict__ rowstart, const int* __restrict__ bs, int n) {
  int i = blockIdx.x * 64 + threadIdx.x;
  if (i < n) rowstart[i + 1] += bs[blockIdx.x];
  if (i == 0) rowstart[0] = 0;
}

__global__ void scatter_kernel(const int* __restrict__ src, const int* __restrict__ dstp,
                               const int* __restrict__ rowstart, int* __restrict__ cursor,
                               int* __restrict__ csr, int n) {
  int i = blockIdx.x * blockDim.x + threadIdx.x;
  if (i < n) {
    int d = dstp[i];
    int pos = atomicAdd(&cursor[d], 1);
    csr[rowstart[d] + pos] = src[i];
  }
}

__global__ void sort_kernel(const int* __restrict__ rowstart, int* __restrict__ csr, int n) {
  int i = blockIdx.x * blockDim.x + threadIdx.x;
  if (i >= n) return;
  int a = rowstart[i], b = rowstart[i + 1];
  for (int j = a + 1; j < b; j++) {
    int v = csr[j];
    int k = j - 1;
    while (k >= a && csr[k] > v) { csr[k + 1] = csr[k]; k--; }
    csr[k + 1] = v;
  }
}

// ---------------- f32 GEMM: C[M,Nout] = A[M,128] @ B[128,Nout] ----------------
__global__ __launch_bounds__(256) void gemm_f32(const float* __restrict__ A,
                                                const float* __restrict__ B,
                                                float* __restrict__ C, int M, int Nout) {
  __shared__ float As[128][66];
  __shared__ float Bs[128][64];
  const int t = threadIdx.x;
  const int row0 = blockIdx.x * 64, col0 = blockIdx.y * 64;
#pragma unroll
  for (int i = 0; i < 8; i++) {
    int idx = t + i * 256;
    int r = idx >> 5, kq = (idx & 31) * 4;
    float4 v = make_float4(0.f, 0.f, 0.f, 0.f);
    if (row0 + r < M) v = *(const float4*)(A + (size_t)(row0 + r) * 128 + kq);
    As[kq + 0][r] = v.x; As[kq + 1][r] = v.y; As[kq + 2][r] = v.z; As[kq + 3][r] = v.w;
  }
#pragma unroll
  for (int i = 0; i < 8; i++) {
    int idx = t + i * 256;
    int k = idx >> 4, c = (idx & 15) * 4;
    *(float4*)(&Bs[k][c]) = *(const float4*)(B + (size_t)k * Nout + col0 + c);
  }
  __syncthreads();
  const int tx = (t & 15) * 4, ty = (t >> 4) * 4;
  float acc[4][4] = {};
#pragma unroll 8
  for (int k = 0; k < 128; k++) {
    float2 a01 = *(const float2*)(&As[k][ty]);
    float2 a23 = *(const float2*)(&As[k][ty + 2]);
    float4 bv = *(const float4*)(&Bs[k][tx]);
    float a[4] = {a01.x, a01.y, a23.x, a23.y};
    float bb[4] = {bv.x, bv.y, bv.z, bv.w};
#pragma unroll
    for (int i = 0; i < 4; i++)
#pragma unroll
      for (int j = 0; j < 4; j++) acc[i][j] = fmaf(a[i], bb[j], acc[i][j]);
  }
#pragma unroll
  for (int i = 0; i < 4; i++) {
    int r = row0 + ty + i;
    if (r < M)
      *(float4*)(C + (size_t)r * Nout + col0 + tx) =
          make_float4(acc[i][0], acc[i][1], acc[i][2], acc[i][3]);
  }
}

// ---------------- fused GATv2 aggregation ----------------
// one block per dst node; one wave per head; xr computed inline.
template <int H, bool RELU>
__global__ __launch_bounds__(H * 64) void agg_kernel(
    const float* __restrict__ h_in, const float* __restrict__ xl,
    const float* __restrict__ Wr, const float* __restrict__ att,
    const float* __restrict__ bias, const int* __restrict__ csr,
    const int* __restrict__ rowstart, float* __restrict__ h_out) {
  const int dst = blockIdx.x;
  const int HC = H * DH;
  __shared__ float hs[DH];
  __shared__ float headout[H][DH];
  if (threadIdx.x < DH) hs[threadIdx.x] = h_in[(size_t)dst * DH + threadIdx.x];
  __syncthreads();
  const int h = threadIdx.x >> 6;
  const int lane = threadIdx.x & 63;
  const int c0 = lane * 2;

  // xr[dst][h][c0..c0+1] inline: sum_k h_in[dst][k] * Wr[k][h*DH + c]
  float xr0 = 0.f, xr1 = 0.f;
  const float* Wrh = Wr + h * DH + c0;
#pragma unroll 4
  for (int k = 0; k < DH; k++) {
    float hk = hs[k];
    float2 w = *(const float2*)(Wrh + (size_t)k * HC);
    xr0 = fmaf(hk, w.x, xr0);
    xr1 = fmaf(hk, w.y, xr1);
  }
  float2 attv = *(const float2*)(att + h * DH + c0);

  // self loop (src == dst) initializes the online softmax
  float2 xs = *(const float2*)(xl + (size_t)dst * HC + h * DH + c0);
  float z0 = xs.x + xr0; z0 = z0 > 0.f ? z0 : 0.2f * z0;
  float z1 = xs.y + xr1; z1 = z1 > 0.f ? z1 : 0.2f * z1;
  float m = wave_sum(z0 * attv.x + z1 * attv.y);
  float s = 1.f;
  float acc0 = xs.x, acc1 = xs.y;

  const int js = rowstart[dst], je = rowstart[dst + 1];
  for (int j = js; j < je; j++) {
    int src = csr[j];
    float2 xv = *(const float2*)(xl + (size_t)src * HC + h * DH + c0);
    float y0 = xv.x + xr0; y0 = y0 > 0.f ? y0 : 0.2f * y0;
    float y1 = xv.y + xr1; y1 = y1 > 0.f ? y1 : 0.2f * y1;
    float e = wave_sum(y0 * attv.x + y1 * attv.y);
    float mn = fmaxf(m, e);
    float sc = __expf(m - mn);
    float p = __expf(e - mn);
    s = s * sc + p;
    acc0 = acc0 * sc + p * xv.x;
    acc1 = acc1 * sc + p * xv.y;
    m = mn;
  }
  float inv = 1.f / s;
  headout[h][c0] = acc0 * inv;
  headout[h][c0 + 1] = acc1 * inv;
  __syncthreads();
  if (threadIdx.x < DH) {
    int c = threadIdx.x;
    float sum = 0.f;
#pragma unroll
    for (int hh = 0; hh < H; hh++) sum += headout[hh][c];
    float r = sum * (1.f / H) + bias[c];
    if (RELU) r = fmaxf(r, 0.f);
    h_out[(size_t)dst * DH + c] = r + hs[c];
  }
}

extern "C" void kernel_launch(void* const* d_in, const int* in_sizes, int n_in,
                              void* d_out, int out_size, void* d_ws, size_t ws_size,
                              hipStream_t stream) {
  const float* x = (const float*)d_in[0];
  const int* ei = (const int*)d_in[1];
  const float* Wl1 = (const float*)d_in[2];
  const float* Wr1 = (const float*)d_in[3];
  const float* att1 = (const float*)d_in[4];
  const float* b1 = (const float*)d_in[5];
  const float* Wl2 = (const float*)d_in[6];
  const float* Wr2 = (const float*)d_in[7];
  const float* att2 = (const float*)d_in[8];
  const float* b2 = (const float*)d_in[9];
  const float* Wl3 = (const float*)d_in[10];
  const float* Wr3 = (const float*)d_in[11];
  const float* att3 = (const float*)d_in[12];
  const float* b3 = (const float*)d_in[13];
  float* out = (float*)d_out;

  float* ws = (float*)d_ws;
  float* xl = ws;                                   // 20000*1024
  float* h1 = xl + (size_t)NN * 1024;               // 20000*128
  float* h2 = h1 + (size_t)NN * DH;                 // 20000*128
  int* deg = (int*)(h2 + (size_t)NN * DH);          // NN
  int* cursor = deg + NN;                           // NN
  int* rowstart = cursor + NN;                      // NN+1
  int* csr = rowstart + NN + 1;                     // NE
  int* bs = csr + NE;                               // 313

  const int* esrc = ei;
  const int* edst = ei + NE;

  hipMemsetAsync(deg, 0, sizeof(int) * 2 * NN, stream);  // deg + cursor
  count_kernel<<<(NE + 255) / 256, 256, 0, stream>>>(edst, deg, NE);
  int nb = (NN + 63) / 64;
  scan_phase1<<<nb, 64, 0, stream>>>(deg, rowstart, bs, NN);
  scan_phase2<<<1, 64, 0, stream>>>(bs, nb);
  scan_phase3<<<nb, 64, 0, stream>>>(rowstart, bs, NN);
  scatter_kernel<<<(NE + 255) / 256, 256, 0, stream>>>(esrc, edst, rowstart, cursor, csr, NE);
  sort_kernel<<<(NN + 255) / 256, 256, 0, stream>>>(rowstart, csr, NN);

  dim3 g8((NN + 63) / 64, 16);
  dim3 g4((NN + 63) / 64, 8);

  // layer 1
  gemm_f32<<<g8, 256, 0, stream>>>(x, Wl1, xl, NN, 1024);
  agg_kernel<8, true><<<NN, 512, 0, stream>>>(x, xl, Wr1, att1, b1, csr, rowstart, h1);
  // layer 2
  gemm_f32<<<g8, 256, 0, stream>>>(h1, Wl2, xl, NN, 1024);
  agg_kernel<8, true><<<NN, 512, 0, stream>>>(h1, xl, Wr2, att2, b2, csr, rowstart, h2);
  // layer 3
  gemm_f32<<<g4, 256, 0, stream>>>(h2, Wl3, xl, NN, 512);
  agg_kernel<4, false><<<NN, 256, 0, stream>>>(h2, xl, Wr3, att3, b3, csr, rowstart, out);
}

// Round 2
// 815.688 us; speedup vs baseline: 2.2017x; 2.2017x over previous
//
#include <hip/hip_runtime.h>
#include <math.h>

#define NN 20000
#define NE 160000
#define DH 128

// ---------------- CSR build ----------------
__global__ void count_kernel(const int* __restrict__ dst, int* __restrict__ deg, int n) {
  int i = blockIdx.x * blockDim.x + threadIdx.x;
  if (i < n) atomicAdd(&deg[dst[i]], 1);
}

__global__ void scan_phase1(const int* __restrict__ deg, int* __restrict__ rowstart,
                            int* __restrict__ bs, int n) {
  int lane = threadIdx.x;
  int i = blockIdx.x * 64 + lane;
  int v = (i < n) ? deg[i] : 0;
#pragma unroll
  for (int off = 1; off < 64; off <<= 1) {
    int u = __shfl_up(v, off, 64);
    if (lane >= off) v += u;
  }
  if (i < n) rowstart[i + 1] = v;  // block-local inclusive
  if (lane == 63) bs[blockIdx.x] = v;
}

__global__ void scan_phase2(int* __restrict__ bs, int nb) {
  int lane = threadIdx.x;
  int carry = 0;
  for (int base = 0; base < nb; base += 64) {
    int i = base + lane;
    int v = (i < nb) ? bs[i] : 0;
    int orig = v;
#pragma unroll
    for (int off = 1; off < 64; off <<= 1) {
      int u = __shfl_up(v, off, 64);
      if (lane >= off) v += u;
    }
    if (i < nb) bs[i] = carry + v - orig;  // exclusive
    carry += __shfl(v, 63, 64);
  }
}

__global__ void scan_phase3(int* __restrict__ rowstart, const int* __restrict__ bs, int n) {
  int i = blockIdx.x * 64 + threadIdx.x;
  if (i < n) rowstart[i + 1] += bs[blockIdx.x];
  if (i == 0) rowstart[0] = 0;
}

__global__ void scatter_kernel(const int* __restrict__ src, const int* __restrict__ dstp,
                               const int* __restrict__ rowstart, int* __restrict__ cursor,
                               int* __restrict__ csr, int n) {
  int i = blockIdx.x * blockDim.x + threadIdx.x;
  if (i < n) {
    int d = dstp[i];
    int pos = atomicAdd(&cursor[d], 1);
    csr[rowstart[d] + pos] = src[i];
  }
}

__global__ void sort_kernel(const int* __restrict__ rowstart, int* __restrict__ csr, int n) {
  int i = blockIdx.x * blockDim.x + threadIdx.x;
  if (i >= n) return;
  int a = rowstart[i], b = rowstart[i + 1];
  for (int j = a + 1; j < b; j++) {
    int v = csr[j];
    int k = j - 1;
    while (k >= a && csr[k] > v) { csr[k + 1] = csr[k]; k--; }
    csr[k + 1] = v;
  }
}

// ---------------- f32 GEMM: C[M,Nout] = A[M,128] @ B[128,Nout] ----------------
__global__ __launch_bounds__(256) void gemm_f32(const float* __restrict__ A,
                                                const float* __restrict__ B,
                                                float* __restrict__ C, int M, int Nout) {
  __shared__ float As[128][66];
  __shared__ float Bs[128][64];
  const int t = threadIdx.x;
  const int row0 = blockIdx.x * 64, col0 = blockIdx.y * 64;
#pragma unroll
  for (int i = 0; i < 8; i++) {
    int idx = t + i * 256;
    int r = idx >> 5, kq = (idx & 31) * 4;
    float4 v = make_float4(0.f, 0.f, 0.f, 0.f);
    if (row0 + r < M) v = *(const float4*)(A + (size_t)(row0 + r) * 128 + kq);
    As[kq + 0][r] = v.x; As[kq + 1][r] = v.y; As[kq + 2][r] = v.z; As[kq + 3][r] = v.w;
  }
#pragma unroll
  for (int i = 0; i < 8; i++) {
    int idx = t + i * 256;
    int k = idx >> 4, c = (idx & 15) * 4;
    *(float4*)(&Bs[k][c]) = *(const float4*)(B + (size_t)k * Nout + col0 + c);
  }
  __syncthreads();
  const int tx = (t & 15) * 4, ty = (t >> 4) * 4;
  float acc[4][4] = {};
#pragma unroll 8
  for (int k = 0; k < 128; k++) {
    float2 a01 = *(const float2*)(&As[k][ty]);
    float2 a23 = *(const float2*)(&As[k][ty + 2]);
    float4 bv = *(const float4*)(&Bs[k][tx]);
    float a[4] = {a01.x, a01.y, a23.x, a23.y};
    float bb[4] = {bv.x, bv.y, bv.z, bv.w};
#pragma unroll
    for (int i = 0; i < 4; i++)
#pragma unroll
      for (int j = 0; j < 4; j++) acc[i][j] = fmaf(a[i], bb[j], acc[i][j]);
  }
#pragma unroll
  for (int i = 0; i < 4; i++) {
    int r = row0 + ty + i;
    if (r < M)
      *(float4*)(C + (size_t)r * Nout + col0 + tx) =
          make_float4(acc[i][0], acc[i][1], acc[i][2], acc[i][3]);
  }
}

// ---------------- fused GATv2 aggregation ----------------
// one block per dst node; one wave per head; 4 edges in flight per wave
// (16-lane subgroups, 8 channels per lane), flash-merge across subgroups.
template <int H, bool RELU>
__global__ __launch_bounds__(H * 64) void agg_kernel(
    const float* __restrict__ h_in, const float* __restrict__ xl,
    const float* __restrict__ xr, const float* __restrict__ att,
    const float* __restrict__ bias, const int* __restrict__ csr,
    const int* __restrict__ rowstart, float* __restrict__ h_out) {
  const int dst = blockIdx.x;
  const int HC = H * DH;
  __shared__ float hs[DH];
  __shared__ float headout[H][DH];
  if (threadIdx.x < DH) hs[threadIdx.x] = h_in[(size_t)dst * DH + threadIdx.x];

  const int h = threadIdx.x >> 6;
  const int lane = threadIdx.x & 63;
  const int g = lane >> 4;   // subgroup (edge slot) 0..3
  const int u = lane & 15;   // lane within subgroup
  const int c0 = u * 8;      // 8 channels per lane

  float xrv[8], attv[8];
  {
    const float* xrp = xr + (size_t)dst * HC + h * DH + c0;
    *(float4*)(xrv) = *(const float4*)(xrp);
    *(float4*)(xrv + 4) = *(const float4*)(xrp + 4);
    const float* ap = att + h * DH + c0;
    *(float4*)(attv) = *(const float4*)(ap);
    *(float4*)(attv + 4) = *(const float4*)(ap + 4);
  }

  float m = -1e30f, s = 0.f;
  float acc[8] = {};

  const int js = rowstart[dst], je = rowstart[dst + 1];

  // subgroup 0 seeds with the self loop (src == dst); others start empty
  if (g == 0) {
    const float* xp = xl + (size_t)dst * HC + h * DH + c0;
    float xv[8];
    *(float4*)(xv) = *(const float4*)(xp);
    *(float4*)(xv + 4) = *(const float4*)(xp + 4);
    float e = 0.f;
#pragma unroll
    for (int q = 0; q < 8; q++) {
      float z = xv[q] + xrv[q];
      z = z > 0.f ? z : 0.2f * z;
      e += z * attv[q];
    }
#pragma unroll
    for (int off = 1; off < 16; off <<= 1) e += __shfl_xor(e, off, 64);
    m = e; s = 1.f;
#pragma unroll
    for (int q = 0; q < 8; q++) acc[q] = xv[q];
  }

  for (int j = js + g; j < je; j += 4) {
    int src = csr[j];
    const float* xp = xl + (size_t)src * HC + h * DH + c0;
    float xv[8];
    *(float4*)(xv) = *(const float4*)(xp);
    *(float4*)(xv + 4) = *(const float4*)(xp + 4);
    float e = 0.f;
#pragma unroll
    for (int q = 0; q < 8; q++) {
      float z = xv[q] + xrv[q];
      z = z > 0.f ? z : 0.2f * z;
      e += z * attv[q];
    }
#pragma unroll
    for (int off = 1; off < 16; off <<= 1) e += __shfl_xor(e, off, 64);
    float mn = fmaxf(m, e);         // m=-1e30 sentinel: exp(-huge)=0, no NaN
    float a = __expf(m - mn);
    float p = __expf(e - mn);
    s = s * a + p;
#pragma unroll
    for (int q = 0; q < 8; q++) acc[q] = acc[q] * a + p * xv[q];
    m = mn;
  }

  // flash-merge subgroups: xor 16, then xor 32
#pragma unroll
  for (int off = 16; off < 64; off <<= 1) {
    float mo = __shfl_xor(m, off, 64);
    float so = __shfl_xor(s, off, 64);
    float ao[8];
#pragma unroll
    for (int q = 0; q < 8; q++) ao[q] = __shfl_xor(acc[q], off, 64);
    float mn = fmaxf(m, mo);
    float a = __expf(m - mn);       // both -1e30 -> exp(0)=1, s=0 stays 0
    float b = __expf(mo - mn);
    s = s * a + so * b;
#pragma unroll
    for (int q = 0; q < 8; q++) acc[q] = acc[q] * a + ao[q] * b;
    m = mn;
  }

  if (g == 0) {
    float inv = 1.f / s;
#pragma unroll
    for (int q = 0; q < 8; q++) headout[h][c0 + q] = acc[q] * inv;
  }
  __syncthreads();
  if (threadIdx.x < DH) {
    int c = threadIdx.x;
    float sum = 0.f;
#pragma unroll
    for (int hh = 0; hh < H; hh++) sum += headout[hh][c];
    float r = sum * (1.f / H) + bias[c];
    if (RELU) r = fmaxf(r, 0.f);
    h_out[(size_t)dst * DH + c] = r + hs[c];
  }
}

extern "C" void kernel_launch(void* const* d_in, const int* in_sizes, int n_in,
                              void* d_out, int out_size, void* d_ws, size_t ws_size,
                              hipStream_t stream) {
  const float* x = (const float*)d_in[0];
  const int* ei = (const int*)d_in[1];
  const float* Wl1 = (const float*)d_in[2];
  const float* Wr1 = (const float*)d_in[3];
  const float* att1 = (const float*)d_in[4];
  const float* b1 = (const float*)d_in[5];
  const float* Wl2 = (const float*)d_in[6];
  const float* Wr2 = (const float*)d_in[7];
  const float* att2 = (const float*)d_in[8];
  const float* b2 = (const float*)d_in[9];
  const float* Wl3 = (const float*)d_in[10];
  const float* Wr3 = (const float*)d_in[11];
  const float* att3 = (const float*)d_in[12];
  const float* b3 = (const float*)d_in[13];
  float* out = (float*)d_out;

  float* ws = (float*)d_ws;
  float* xl = ws;                                   // 20000*1024
  float* xr = xl + (size_t)NN * 1024;               // 20000*1024
  float* h1 = xr + (size_t)NN * 1024;               // 20000*128
  float* h2 = h1 + (size_t)NN * DH;                 // 20000*128
  int* deg = (int*)(h2 + (size_t)NN * DH);          // NN
  int* cursor = deg + NN;                           // NN
  int* rowstart = cursor + NN;                      // NN+1
  int* csr = rowstart + NN + 1;                     // NE
  int* bs = csr + NE;                               // 313

  const int* esrc = ei;
  const int* edst = ei + NE;

  hipMemsetAsync(deg, 0, sizeof(int) * 2 * NN, stream);  // deg + cursor
  count_kernel<<<(NE + 255) / 256, 256, 0, stream>>>(edst, deg, NE);
  int nb = (NN + 63) / 64;
  scan_phase1<<<nb, 64, 0, stream>>>(deg, rowstart, bs, NN);
  scan_phase2<<<1, 64, 0, stream>>>(bs, nb);
  scan_phase3<<<nb, 64, 0, stream>>>(rowstart, bs, NN);
  scatter_kernel<<<(NE + 255) / 256, 256, 0, stream>>>(esrc, edst, rowstart, cursor, csr, NE);
  sort_kernel<<<(NN + 255) / 256, 256, 0, stream>>>(rowstart, csr, NN);

  dim3 g8((NN + 63) / 64, 16);
  dim3 g4((NN + 63) / 64, 8);

  // layer 1
  gemm_f32<<<g8, 256, 0, stream>>>(x, Wl1, xl, NN, 1024);
  gemm_f32<<<g8, 256, 0, stream>>>(x, Wr1, xr, NN, 1024);
  agg_kernel<8, true><<<NN, 512, 0, stream>>>(x, xl, xr, att1, b1, csr, rowstart, h1);
  // layer 2
  gemm_f32<<<g8, 256, 0, stream>>>(h1, Wl2, xl, NN, 1024);
  gemm_f32<<<g8, 256, 0, stream>>>(h1, Wr2, xr, NN, 1024);
  agg_kernel<8, true><<<NN, 512, 0, stream>>>(h1, xl, xr, att2, b2, csr, rowstart, h2);
  // layer 3
  gemm_f32<<<g4, 256, 0, stream>>>(h2, Wl3, xl, NN, 512);
  gemm_f32<<<g4, 256, 0, stream>>>(h2, Wr3, xr, NN, 512);
  agg_kernel<4, false><<<NN, 256, 0, stream>>>(h2, xl, xr, att3, b3, csr, rowstart, out);
}

// Round 3
// 513.237 us; speedup vs baseline: 3.4992x; 1.5893x over previous
//
#include <hip/hip_runtime.h>
#include <math.h>

#define NN 20000
#define NE 160000
#define DH 128

typedef unsigned short u16;
typedef u16 u16x8 __attribute__((ext_vector_type(8)));
typedef u16 u16x4 __attribute__((ext_vector_type(4)));
typedef short short8 __attribute__((ext_vector_type(8)));
typedef float f32x4 __attribute__((ext_vector_type(4)));

__device__ __forceinline__ u16 f2bf(float f) {
  unsigned x = __float_as_uint(f);
  unsigned r = (x + 0x7FFFu + ((x >> 16) & 1u)) >> 16;  // RNE
  return (u16)r;
}
__device__ __forceinline__ float bf2f(u16 u) {
  return __uint_as_float(((unsigned)u) << 16);
}

// ---------------- CSR build ----------------
__global__ void count_kernel(const int* __restrict__ dst, int* __restrict__ deg, int n) {
  int i = blockIdx.x * blockDim.x + threadIdx.x;
  if (i < n) atomicAdd(&deg[dst[i]], 1);
}

__global__ void scan_phase1(const int* __restrict__ deg, int* __restrict__ rowstart,
                            int* __restrict__ bs, int n) {
  int lane = threadIdx.x;
  int i = blockIdx.x * 64 + lane;
  int v = (i < n) ? deg[i] : 0;
#pragma unroll
  for (int off = 1; off < 64; off <<= 1) {
    int u = __shfl_up(v, off, 64);
    if (lane >= off) v += u;
  }
  if (i < n) rowstart[i + 1] = v;
  if (lane == 63) bs[blockIdx.x] = v;
}

__global__ void scan_phase2(int* __restrict__ bs, int nb) {
  int lane = threadIdx.x;
  int carry = 0;
  for (int base = 0; base < nb; base += 64) {
    int i = base + lane;
    int v = (i < nb) ? bs[i] : 0;
    int orig = v;
#pragma unroll
    for (int off = 1; off < 64; off <<= 1) {
      int u = __shfl_up(v, off, 64);
      if (lane >= off) v += u;
    }
    if (i < nb) bs[i] = carry + v - orig;
    carry += __shfl(v, 63, 64);
  }
}

__global__ void scan_phase3(int* __restrict__ rowstart, const int* __restrict__ bs, int n) {
  int i = blockIdx.x * 64 + threadIdx.x;
  if (i < n) rowstart[i + 1] += bs[blockIdx.x];
  if (i == 0) rowstart[0] = 0;
}

__global__ void scatter_kernel(const int* __restrict__ src, const int* __restrict__ dstp,
                               const int* __restrict__ rowstart, int* __restrict__ cursor,
                               int* __restrict__ csr, int n) {
  int i = blockIdx.x * blockDim.x + threadIdx.x;
  if (i < n) {
    int d = dstp[i];
    int pos = atomicAdd(&cursor[d], 1);
    csr[rowstart[d] + pos] = src[i];
  }
}

__global__ void sort_kernel(const int* __restrict__ rowstart, int* __restrict__ csr, int n) {
  int i = blockIdx.x * blockDim.x + threadIdx.x;
  if (i >= n) return;
  int a = rowstart[i], b = rowstart[i + 1];
  for (int j = a + 1; j < b; j++) {
    int v = csr[j];
    int k = j - 1;
    while (k >= a && csr[k] > v) { csr[k + 1] = csr[k]; k--; }
    csr[k + 1] = v;
  }
}

// ---------------- conversions ----------------
__global__ void conv_bf_kernel(const float* __restrict__ X, u16* __restrict__ XB, int n4) {
  int i = blockIdx.x * blockDim.x + threadIdx.x;
  if (i < n4) {
    float4 v = *(const float4*)(X + (size_t)i * 4);
    u16x4 o = {f2bf(v.x), f2bf(v.y), f2bf(v.z), f2bf(v.w)};
    *(u16x4*)(XB + (size_t)i * 4) = o;
  }
}

// W [128][HC] f32 -> WT [HC][128] bf16
__global__ void transconv_kernel(const float* __restrict__ W, u16* __restrict__ WT, int HC) {
  int i = blockIdx.x * blockDim.x + threadIdx.x;
  if (i < HC * 128) {
    int c = i >> 7, k = i & 127;
    WT[i] = f2bf(W[(size_t)k * HC + c]);
  }
}

// ---------------- bf16 MFMA GEMM: C[M,Nout] = A[M,128] @ BT[Nout,128]^T ----------------
// no LDS: fragment layouts match row-major A / BT rows directly (16B/lane loads)
__global__ __launch_bounds__(256) void gemm_bf16(const u16* __restrict__ A,
                                                 const u16* __restrict__ BT,
                                                 u16* __restrict__ C, int M, int Nout) {
  const int w = threadIdx.x >> 6, lane = threadIdx.x & 63;
  const int wm = w >> 1, wn = w & 1;
  const int row0 = blockIdx.x * 128 + wm * 64;
  const int col0 = blockIdx.y * 128 + wn * 64;
  const int lr = lane & 15, lk = (lane >> 4) * 8;

  f32x4 acc[4][4] = {};
  const u16* Arow[4];
  const u16* Brow[4];
#pragma unroll
  for (int m = 0; m < 4; m++) {
    int r = row0 + m * 16 + lr;
    r = r < M ? r : M - 1;
    Arow[m] = A + (size_t)r * 128 + lk;
  }
#pragma unroll
  for (int n = 0; n < 4; n++) {
    int c = col0 + n * 16 + lr;
    Brow[n] = BT + (size_t)c * 128 + lk;
  }
#pragma unroll
  for (int ks = 0; ks < 4; ks++) {
    short8 a[4], b[4];
#pragma unroll
    for (int m = 0; m < 4; m++) a[m] = *(const short8*)(const void*)(Arow[m] + ks * 32);
#pragma unroll
    for (int n = 0; n < 4; n++) b[n] = *(const short8*)(const void*)(Brow[n] + ks * 32);
#pragma unroll
    for (int m = 0; m < 4; m++)
#pragma unroll
      for (int n = 0; n < 4; n++)
        acc[m][n] = __builtin_amdgcn_mfma_f32_16x16x32_bf16(a[m], b[n], acc[m][n], 0, 0, 0);
  }
#pragma unroll
  for (int m = 0; m < 4; m++) {
    int rbase = row0 + m * 16 + (lane >> 4) * 4;
#pragma unroll
    for (int r = 0; r < 4; r++) {
      int rr = rbase + r;
      if (rr < M) {
#pragma unroll
        for (int n = 0; n < 4; n++) {
          int c = col0 + n * 16 + lr;
          C[(size_t)rr * Nout + c] = f2bf(acc[m][n][r]);
        }
      }
    }
  }
}

// ---------------- fused GATv2 aggregation (bf16 xl/xr) ----------------
template <int H, bool RELU, bool WBF>
__global__ __launch_bounds__(H * 64) void agg_kernel(
    const float* __restrict__ h_in, const u16* __restrict__ xl,
    const u16* __restrict__ xr, const float* __restrict__ att,
    const float* __restrict__ bias, const int* __restrict__ csr,
    const int* __restrict__ rowstart, float* __restrict__ h_out,
    u16* __restrict__ hbf) {
  const int dst = blockIdx.x;
  const int HC = H * DH;
  __shared__ float hs[DH];
  __shared__ float headout[H][DH];
  if (threadIdx.x < DH) hs[threadIdx.x] = h_in[(size_t)dst * DH + threadIdx.x];

  const int h = threadIdx.x >> 6;
  const int lane = threadIdx.x & 63;
  const int g = lane >> 4;   // edge slot 0..3
  const int u = lane & 15;
  const int c0 = u * 8;

  float xrv[8], attv[8];
  {
    u16x8 raw = *(const u16x8*)(xr + (size_t)dst * HC + h * DH + c0);
#pragma unroll
    for (int q = 0; q < 8; q++) xrv[q] = bf2f(raw[q]);
    const float* ap = att + h * DH + c0;
    *(float4*)(attv) = *(const float4*)(ap);
    *(float4*)(attv + 4) = *(const float4*)(ap + 4);
  }

  float m = -1e30f, s = 0.f;
  float acc[8] = {};

  const int js = rowstart[dst], je = rowstart[dst + 1];

  if (g == 0) {  // self loop
    u16x8 raw = *(const u16x8*)(xl + (size_t)dst * HC + h * DH + c0);
    float xv[8];
#pragma unroll
    for (int q = 0; q < 8; q++) xv[q] = bf2f(raw[q]);
    float e = 0.f;
#pragma unroll
    for (int q = 0; q < 8; q++) {
      float z = xv[q] + xrv[q];
      z = z > 0.f ? z : 0.2f * z;
      e += z * attv[q];
    }
#pragma unroll
    for (int off = 1; off < 16; off <<= 1) e += __shfl_xor(e, off, 64);
    m = e; s = 1.f;
#pragma unroll
    for (int q = 0; q < 8; q++) acc[q] = xv[q];
  }

  for (int j = js + g; j < je; j += 4) {
    int src = csr[j];
    u16x8 raw = *(const u16x8*)(xl + (size_t)src * HC + h * DH + c0);
    float xv[8];
#pragma unroll
    for (int q = 0; q < 8; q++) xv[q] = bf2f(raw[q]);
    float e = 0.f;
#pragma unroll
    for (int q = 0; q < 8; q++) {
      float z = xv[q] + xrv[q];
      z = z > 0.f ? z : 0.2f * z;
      e += z * attv[q];
    }
#pragma unroll
    for (int off = 1; off < 16; off <<= 1) e += __shfl_xor(e, off, 64);
    float mn = fmaxf(m, e);
    float a = __expf(m - mn);
    float p = __expf(e - mn);
    s = s * a + p;
#pragma unroll
    for (int q = 0; q < 8; q++) acc[q] = acc[q] * a + p * xv[q];
    m = mn;
  }

#pragma unroll
  for (int off = 16; off < 64; off <<= 1) {
    float mo = __shfl_xor(m, off, 64);
    float so = __shfl_xor(s, off, 64);
    float ao[8];
#pragma unroll
    for (int q = 0; q < 8; q++) ao[q] = __shfl_xor(acc[q], off, 64);
    float mn = fmaxf(m, mo);
    float a = __expf(m - mn);
    float b = __expf(mo - mn);
    s = s * a + so * b;
#pragma unroll
    for (int q = 0; q < 8; q++) acc[q] = acc[q] * a + ao[q] * b;
    m = mn;
  }

  if (g == 0) {
    float inv = 1.f / s;
#pragma unroll
    for (int q = 0; q < 8; q++) headout[h][c0 + q] = acc[q] * inv;
  }
  __syncthreads();
  if (threadIdx.x < DH) {
    int c = threadIdx.x;
    float sum = 0.f;
#pragma unroll
    for (int hh = 0; hh < H; hh++) sum += headout[hh][c];
    float r = sum * (1.f / H) + bias[c];
    if (RELU) r = fmaxf(r, 0.f);
    float o = r + hs[c];
    h_out[(size_t)dst * DH + c] = o;
    if (WBF) hbf[(size_t)dst * DH + c] = f2bf(o);
  }
}

extern "C" void kernel_launch(void* const* d_in, const int* in_sizes, int n_in,
                              void* d_out, int out_size, void* d_ws, size_t ws_size,
                              hipStream_t stream) {
  const float* x = (const float*)d_in[0];
  const int* ei = (const int*)d_in[1];
  const float* Wl1 = (const float*)d_in[2];
  const float* Wr1 = (const float*)d_in[3];
  const float* att1 = (const float*)d_in[4];
  const float* b1 = (const float*)d_in[5];
  const float* Wl2 = (const float*)d_in[6];
  const float* Wr2 = (const float*)d_in[7];
  const float* att2 = (const float*)d_in[8];
  const float* b2 = (const float*)d_in[9];
  const float* Wl3 = (const float*)d_in[10];
  const float* Wr3 = (const float*)d_in[11];
  const float* att3 = (const float*)d_in[12];
  const float* b3 = (const float*)d_in[13];
  float* out = (float*)d_out;

  char* p = (char*)d_ws;
  u16* xl_bf = (u16*)p; p += (size_t)NN * 1024 * 2;
  u16* xr_bf = (u16*)p; p += (size_t)NN * 1024 * 2;
  u16* xbf   = (u16*)p; p += (size_t)NN * DH * 2;
  u16* h1bf  = (u16*)p; p += (size_t)NN * DH * 2;
  u16* h2bf  = (u16*)p; p += (size_t)NN * DH * 2;
  u16* WlT1  = (u16*)p; p += (size_t)1024 * 128 * 2;
  u16* WrT1  = (u16*)p; p += (size_t)1024 * 128 * 2;
  u16* WlT2  = (u16*)p; p += (size_t)1024 * 128 * 2;
  u16* WrT2  = (u16*)p; p += (size_t)1024 * 128 * 2;
  u16* WlT3  = (u16*)p; p += (size_t)512 * 128 * 2;
  u16* WrT3  = (u16*)p; p += (size_t)512 * 128 * 2;
  float* h1  = (float*)p; p += (size_t)NN * DH * 4;
  float* h2  = (float*)p; p += (size_t)NN * DH * 4;
  int* deg      = (int*)p; p += (size_t)NN * 4;
  int* cursor   = (int*)p; p += (size_t)NN * 4;
  int* rowstart = (int*)p; p += (size_t)(NN + 1) * 4;
  int* csr      = (int*)p; p += (size_t)NE * 4;
  int* bs       = (int*)p;

  const int* esrc = ei;
  const int* edst = ei + NE;

  hipMemsetAsync(deg, 0, sizeof(int) * 2 * NN, stream);  // deg + cursor
  count_kernel<<<(NE + 255) / 256, 256, 0, stream>>>(edst, deg, NE);
  int nb = (NN + 63) / 64;
  scan_phase1<<<nb, 64, 0, stream>>>(deg, rowstart, bs, NN);
  scan_phase2<<<1, 64, 0, stream>>>(bs, nb);
  scan_phase3<<<nb, 64, 0, stream>>>(rowstart, bs, NN);
  scatter_kernel<<<(NE + 255) / 256, 256, 0, stream>>>(esrc, edst, rowstart, cursor, csr, NE);
  sort_kernel<<<(NN + 255) / 256, 256, 0, stream>>>(rowstart, csr, NN);

  // conversions
  conv_bf_kernel<<<(NN * DH / 4 + 255) / 256, 256, 0, stream>>>(x, xbf, NN * DH / 4);
  transconv_kernel<<<(1024 * 128 + 255) / 256, 256, 0, stream>>>(Wl1, WlT1, 1024);
  transconv_kernel<<<(1024 * 128 + 255) / 256, 256, 0, stream>>>(Wr1, WrT1, 1024);
  transconv_kernel<<<(1024 * 128 + 255) / 256, 256, 0, stream>>>(Wl2, WlT2, 1024);
  transconv_kernel<<<(1024 * 128 + 255) / 256, 256, 0, stream>>>(Wr2, WrT2, 1024);
  transconv_kernel<<<(512 * 128 + 255) / 256, 256, 0, stream>>>(Wl3, WlT3, 512);
  transconv_kernel<<<(512 * 128 + 255) / 256, 256, 0, stream>>>(Wr3, WrT3, 512);

  dim3 g8((NN + 127) / 128, 8);
  dim3 g4((NN + 127) / 128, 4);

  // layer 1
  gemm_bf16<<<g8, 256, 0, stream>>>(xbf, WlT1, xl_bf, NN, 1024);
  gemm_bf16<<<g8, 256, 0, stream>>>(xbf, WrT1, xr_bf, NN, 1024);
  agg_kernel<8, true, true><<<NN, 512, 0, stream>>>(x, xl_bf, xr_bf, att1, b1, csr, rowstart, h1, h1bf);
  // layer 2
  gemm_bf16<<<g8, 256, 0, stream>>>(h1bf, WlT2, xl_bf, NN, 1024);
  gemm_bf16<<<g8, 256, 0, stream>>>(h1bf, WrT2, xr_bf, NN, 1024);
  agg_kernel<8, true, true><<<NN, 512, 0, stream>>>(h1, xl_bf, xr_bf, att2, b2, csr, rowstart, h2, h2bf);
  // layer 3
  gemm_bf16<<<g4, 256, 0, stream>>>(h2bf, WlT3, xl_bf, NN, 512);
  gemm_bf16<<<g4, 256, 0, stream>>>(h2bf, WrT3, xr_bf, NN, 512);
  agg_kernel<4, false, false><<<NN, 256, 0, stream>>>(h2, xl_bf, xr_bf, att3, b3, csr, rowstart, out, nullptr);
}

// Round 4
// 375.846 us; speedup vs baseline: 4.7784x; 1.3655x over previous
//
#include <hip/hip_runtime.h>
#include <math.h>

#define NN 20000
#define NE 160000
#define DH 128

typedef _Float16 f16;
typedef f16 f16x2 __attribute__((ext_vector_type(2)));
typedef f16 f16x4 __attribute__((ext_vector_type(4)));
typedef f16 f16x8 __attribute__((ext_vector_type(8)));
typedef float f32x4 __attribute__((ext_vector_type(4)));

// ---------------- CSR build ----------------
__global__ void count_kernel(const int* __restrict__ dst, int* __restrict__ deg, int n) {
  int i = blockIdx.x * blockDim.x + threadIdx.x;
  if (i < n) atomicAdd(&deg[dst[i]], 1);
}

__global__ void scan_phase1(const int* __restrict__ deg, int* __restrict__ rowstart,
                            int* __restrict__ bs, int n) {
  int lane = threadIdx.x;
  int i = blockIdx.x * 64 + lane;
  int v = (i < n) ? deg[i] : 0;
#pragma unroll
  for (int off = 1; off < 64; off <<= 1) {
    int u = __shfl_up(v, off, 64);
    if (lane >= off) v += u;
  }
  if (i < n) rowstart[i + 1] = v;
  if (lane == 63) bs[blockIdx.x] = v;
}

__global__ void scan_phase2(int* __restrict__ bs, int nb) {
  int lane = threadIdx.x;
  int carry = 0;
  for (int base = 0; base < nb; base += 64) {
    int i = base + lane;
    int v = (i < nb) ? bs[i] : 0;
    int orig = v;
#pragma unroll
    for (int off = 1; off < 64; off <<= 1) {
      int u = __shfl_up(v, off, 64);
      if (lane >= off) v += u;
    }
    if (i < nb) bs[i] = carry + v - orig;
    carry += __shfl(v, 63, 64);
  }
}

__global__ void scan_phase3(int* __restrict__ rowstart, const int* __restrict__ bs, int n) {
  int i = blockIdx.x * 64 + threadIdx.x;
  if (i < n) rowstart[i + 1] += bs[blockIdx.x];
  if (i == 0) rowstart[0] = 0;
}

__global__ void scatter_kernel(const int* __restrict__ src, const int* __restrict__ dstp,
                               const int* __restrict__ rowstart, int* __restrict__ cursor,
                               int* __restrict__ csr, int n) {
  int i = blockIdx.x * blockDim.x + threadIdx.x;
  if (i < n) {
    int d = dstp[i];
    int pos = atomicAdd(&cursor[d], 1);
    csr[rowstart[d] + pos] = src[i];
  }
}

__global__ void sort_kernel(const int* __restrict__ rowstart, int* __restrict__ csr, int n) {
  int i = blockIdx.x * blockDim.x + threadIdx.x;
  if (i >= n) return;
  int a = rowstart[i], b = rowstart[i + 1];
  for (int j = a + 1; j < b; j++) {
    int v = csr[j];
    int k = j - 1;
    while (k >= a && csr[k] > v) { csr[k + 1] = csr[k]; k--; }
    csr[k + 1] = v;
  }
}

// ---------------- conversions ----------------
__global__ void conv_h_kernel(const float* __restrict__ X, f16* __restrict__ XH, int n4) {
  int i = blockIdx.x * blockDim.x + threadIdx.x;
  if (i < n4) {
    float4 v = *(const float4*)(X + (size_t)i * 4);
    f16x4 o = {(f16)v.x, (f16)v.y, (f16)v.z, (f16)v.w};
    *(f16x4*)(XH + (size_t)i * 4) = o;
  }
}

// W [128][HC] f32 -> WT [HC][128] f16
__global__ void transconv_kernel(const float* __restrict__ W, f16* __restrict__ WT, int HC) {
  int i = blockIdx.x * blockDim.x + threadIdx.x;
  if (i < HC * 128) {
    int c = i >> 7, k = i & 127;
    WT[i] = (f16)W[(size_t)k * HC + c];
  }
}

// ---------------- f16 MFMA GEMM: C[M,Nout] = A[M,128] @ BT[Nout,128]^T ----------------
__global__ __launch_bounds__(256) void gemm_f16(const f16* __restrict__ A,
                                                const f16* __restrict__ BT,
                                                f16* __restrict__ C, int M, int Nout) {
  const int w = threadIdx.x >> 6, lane = threadIdx.x & 63;
  const int wm = w >> 1, wn = w & 1;
  const int row0 = blockIdx.x * 128 + wm * 64;
  const int col0 = blockIdx.y * 128 + wn * 64;
  const int lr = lane & 15, lk = (lane >> 4) * 8;

  f32x4 acc[4][4] = {};
  const f16* Arow[4];
  const f16* Brow[4];
#pragma unroll
  for (int m = 0; m < 4; m++) {
    int r = row0 + m * 16 + lr;
    r = r < M ? r : M - 1;
    Arow[m] = A + (size_t)r * 128 + lk;
  }
#pragma unroll
  for (int n = 0; n < 4; n++) {
    int c = col0 + n * 16 + lr;
    Brow[n] = BT + (size_t)c * 128 + lk;
  }
#pragma unroll
  for (int ks = 0; ks < 4; ks++) {
    f16x8 a[4], b[4];
#pragma unroll
    for (int m = 0; m < 4; m++) a[m] = *(const f16x8*)(Arow[m] + ks * 32);
#pragma unroll
    for (int n = 0; n < 4; n++) b[n] = *(const f16x8*)(Brow[n] + ks * 32);
#pragma unroll
    for (int m = 0; m < 4; m++)
#pragma unroll
      for (int n = 0; n < 4; n++)
        acc[m][n] = __builtin_amdgcn_mfma_f32_16x16x32_f16(a[m], b[n], acc[m][n], 0, 0, 0);
  }
#pragma unroll
  for (int m = 0; m < 4; m++) {
    int rbase = row0 + m * 16 + (lane >> 4) * 4;
#pragma unroll
    for (int r = 0; r < 4; r++) {
      int rr = rbase + r;
      if (rr < M) {
#pragma unroll
        for (int n = 0; n < 4; n++) {
          int c = col0 + n * 16 + lr;
          C[(size_t)rr * Nout + c] = (f16)acc[m][n][r];
        }
      }
    }
  }
}

// ---------------- fused GATv2 aggregation (fp16 packed, subgroup-per-dst) ----------------
__device__ __forceinline__ f16x2 pr(f16x8 v, int q) { return f16x2{v[2 * q], v[2 * q + 1]}; }

__device__ __forceinline__ f16x2 leaky2(f16x2 z) {
  f16x2 zs = z * (f16)0.2f;
  return __builtin_elementwise_max(z, zs);
}

template <int H, bool RELU, bool WH>
__global__ __launch_bounds__(H * 64) void agg_kernel(
    const float* __restrict__ h_in, const f16* __restrict__ xlr, int xroff, int stride,
    const float* __restrict__ att, const float* __restrict__ bias,
    const int* __restrict__ csr, const int* __restrict__ rowstart,
    float* __restrict__ h_out, f16* __restrict__ hh) {
  __shared__ float headout[H][4][DH];
  const int h = threadIdx.x >> 6;
  const int lane = threadIdx.x & 63;
  const int g = lane >> 4, u = lane & 15;
  const int c0 = u * 8;
  const int dst = blockIdx.x * 4 + g;

  const f16* xl = xlr;
  const f16* xr = xlr + xroff;

  f16x2 att2[4], xr2[4];
  {
    float a0[8];
    const float* ap = att + h * DH + c0;
    *(float4*)a0 = *(const float4*)ap;
    *(float4*)(a0 + 4) = *(const float4*)(ap + 4);
#pragma unroll
    for (int q = 0; q < 4; q++) att2[q] = f16x2{(f16)a0[2 * q], (f16)a0[2 * q + 1]};
    f16x8 xrv = *(const f16x8*)(xr + (size_t)dst * stride + h * DH + c0);
#pragma unroll
    for (int q = 0; q < 4; q++) xr2[q] = pr(xrv, q);
  }

  const int js = rowstart[dst], je = rowstart[dst + 1];

  // self loop seed
  float m, s;
  f16x2 acc[4];
  {
    f16x8 xv = *(const f16x8*)(xl + (size_t)dst * stride + h * DH + c0);
    float e = 0.f;
#pragma unroll
    for (int q = 0; q < 4; q++) {
      f16x2 z = leaky2(pr(xv, q) + xr2[q]);
      e = __builtin_amdgcn_fdot2(z, att2[q], e, false);
    }
#pragma unroll
    for (int off = 1; off < 16; off <<= 1) e += __shfl_xor(e, off, 64);
    m = e;
    s = 1.f;
#pragma unroll
    for (int q = 0; q < 4; q++) acc[q] = pr(xv, q);
  }

  // serial edge walk with one-deep prefetch
  f16x8 nv;
  if (js < je) {
    int src0 = csr[js];
    nv = *(const f16x8*)(xl + (size_t)src0 * stride + h * DH + c0);
  }
  for (int j = js; j < je; j++) {
    f16x8 cv = nv;
    if (j + 1 < je) {
      int sn = csr[j + 1];
      nv = *(const f16x8*)(xl + (size_t)sn * stride + h * DH + c0);
    }
    float e = 0.f;
#pragma unroll
    for (int q = 0; q < 4; q++) {
      f16x2 z = leaky2(pr(cv, q) + xr2[q]);
      e = __builtin_amdgcn_fdot2(z, att2[q], e, false);
    }
#pragma unroll
    for (int off = 1; off < 16; off <<= 1) e += __shfl_xor(e, off, 64);
    if (e <= m) {
      float p = __expf(e - m);
      s += p;
      f16 ph = (f16)p;
      f16x2 p2 = {ph, ph};
#pragma unroll
      for (int q = 0; q < 4; q++) acc[q] = pr(cv, q) * p2 + acc[q];
    } else {
      float a = __expf(m - e);
      m = e;
      s = s * a + 1.f;
      f16 ah = (f16)a;
      f16x2 a2 = {ah, ah};
#pragma unroll
      for (int q = 0; q < 4; q++) acc[q] = acc[q] * a2 + pr(cv, q);
    }
  }

  float inv = 1.f / s;
#pragma unroll
  for (int q = 0; q < 4; q++) {
    headout[h][g][c0 + 2 * q] = (float)acc[q][0] * inv;
    headout[h][g][c0 + 2 * q + 1] = (float)acc[q][1] * inv;
  }
  __syncthreads();
  for (int t = threadIdx.x; t < 4 * DH; t += H * 64) {
    int d = t >> 7, c = t & 127;
    float sum = 0.f;
#pragma unroll
    for (int q = 0; q < H; q++) sum += headout[q][d][c];
    float r = sum * (1.f / H) + bias[c];
    if (RELU) r = fmaxf(r, 0.f);
    int node = blockIdx.x * 4 + d;
    float o = r + h_in[(size_t)node * DH + c];
    h_out[(size_t)node * DH + c] = o;
    if (WH) hh[(size_t)node * DH + c] = (f16)o;
  }
}

extern "C" void kernel_launch(void* const* d_in, const int* in_sizes, int n_in,
                              void* d_out, int out_size, void* d_ws, size_t ws_size,
                              hipStream_t stream) {
  const float* x = (const float*)d_in[0];
  const int* ei = (const int*)d_in[1];
  const float* Wl1 = (const float*)d_in[2];
  const float* Wr1 = (const float*)d_in[3];
  const float* att1 = (const float*)d_in[4];
  const float* b1 = (const float*)d_in[5];
  const float* Wl2 = (const float*)d_in[6];
  const float* Wr2 = (const float*)d_in[7];
  const float* att2 = (const float*)d_in[8];
  const float* b2 = (const float*)d_in[9];
  const float* Wl3 = (const float*)d_in[10];
  const float* Wr3 = (const float*)d_in[11];
  const float* att3 = (const float*)d_in[12];
  const float* b3 = (const float*)d_in[13];
  float* out = (float*)d_out;

  char* p = (char*)d_ws;
  f16* xlr = (f16*)p; p += (size_t)NN * 2048 * 2;
  f16* xh  = (f16*)p; p += (size_t)NN * DH * 2;
  f16* h1h = (f16*)p; p += (size_t)NN * DH * 2;
  f16* h2h = (f16*)p; p += (size_t)NN * DH * 2;
  f16* WT1 = (f16*)p; p += (size_t)2048 * 128 * 2;
  f16* WT2 = (f16*)p; p += (size_t)2048 * 128 * 2;
  f16* WT3 = (f16*)p; p += (size_t)1024 * 128 * 2;
  float* h1 = (float*)p; p += (size_t)NN * DH * 4;
  float* h2 = (float*)p; p += (size_t)NN * DH * 4;
  int* deg      = (int*)p; p += (size_t)NN * 4;
  int* cursor   = (int*)p; p += (size_t)NN * 4;
  int* rowstart = (int*)p; p += (size_t)(NN + 1) * 4;
  int* csr      = (int*)p; p += (size_t)NE * 4;
  int* bs       = (int*)p;

  const int* esrc = ei;
  const int* edst = ei + NE;

  hipMemsetAsync(deg, 0, sizeof(int) * 2 * NN, stream);  // deg + cursor
  count_kernel<<<(NE + 255) / 256, 256, 0, stream>>>(edst, deg, NE);
  int nb = (NN + 63) / 64;
  scan_phase1<<<nb, 64, 0, stream>>>(deg, rowstart, bs, NN);
  scan_phase2<<<1, 64, 0, stream>>>(bs, nb);
  scan_phase3<<<nb, 64, 0, stream>>>(rowstart, bs, NN);
  scatter_kernel<<<(NE + 255) / 256, 256, 0, stream>>>(esrc, edst, rowstart, cursor, csr, NE);
  sort_kernel<<<(NN + 255) / 256, 256, 0, stream>>>(rowstart, csr, NN);

  // conversions
  conv_h_kernel<<<(NN * DH / 4 + 255) / 256, 256, 0, stream>>>(x, xh, NN * DH / 4);
  transconv_kernel<<<(1024 * 128 + 255) / 256, 256, 0, stream>>>(Wl1, WT1, 1024);
  transconv_kernel<<<(1024 * 128 + 255) / 256, 256, 0, stream>>>(Wr1, WT1 + (size_t)1024 * 128, 1024);
  transconv_kernel<<<(1024 * 128 + 255) / 256, 256, 0, stream>>>(Wl2, WT2, 1024);
  transconv_kernel<<<(1024 * 128 + 255) / 256, 256, 0, stream>>>(Wr2, WT2 + (size_t)1024 * 128, 1024);
  transconv_kernel<<<(512 * 128 + 255) / 256, 256, 0, stream>>>(Wl3, WT3, 512);
  transconv_kernel<<<(512 * 128 + 255) / 256, 256, 0, stream>>>(Wr3, WT3 + (size_t)512 * 128, 512);

  dim3 gA((NN + 127) / 128, 16);
  dim3 gB((NN + 127) / 128, 8);
  const int nblk = NN / 4;  // 5000

  // layer 1
  gemm_f16<<<gA, 256, 0, stream>>>(xh, WT1, xlr, NN, 2048);
  agg_kernel<8, true, true><<<nblk, 512, 0, stream>>>(x, xlr, 1024, 2048, att1, b1, csr, rowstart, h1, h1h);
  // layer 2
  gemm_f16<<<gA, 256, 0, stream>>>(h1h, WT2, xlr, NN, 2048);
  agg_kernel<8, true, true><<<nblk, 512, 0, stream>>>(h1, xlr, 1024, 2048, att2, b2, csr, rowstart, h2, h2h);
  // layer 3
  gemm_f16<<<gB, 256, 0, stream>>>(h2h, WT3, xlr, NN, 1024);
  agg_kernel<4, false, false><<<nblk, 256, 0, stream>>>(h2, xlr, 512, 1024, att3, b3, csr, rowstart, out, nullptr);
}

// Round 5
// 365.655 us; speedup vs baseline: 4.9116x; 1.0279x over previous
//
#include <hip/hip_runtime.h>
#include <math.h>

#define NN 20000
#define NE 160000
#define DH 128

typedef _Float16 f16;
typedef f16 f16x2 __attribute__((ext_vector_type(2)));
typedef f16 f16x4 __attribute__((ext_vector_type(4)));
typedef f16 f16x8 __attribute__((ext_vector_type(8)));
typedef float f32x4 __attribute__((ext_vector_type(4)));

// ---------------- CSR build ----------------
__global__ void count_kernel(const int* __restrict__ dst, int* __restrict__ deg, int n) {
  int i = blockIdx.x * blockDim.x + threadIdx.x;
  if (i < n) atomicAdd(&deg[dst[i]], 1);
}

// single-block scan over n ints: rowstart[i+1] = inclusive_scan(deg)[i]
__global__ __launch_bounds__(1024) void scan_all(const int* __restrict__ deg,
                                                 int* __restrict__ rowstart, int n) {
  __shared__ int wsum[16];
  __shared__ int carryS;
  const int tid = threadIdx.x;
  const int lane = tid & 63, w = tid >> 6;
  if (tid == 0) { carryS = 0; rowstart[0] = 0; }
  __syncthreads();
  for (int base = 0; base < n; base += 1024) {
    int i = base + tid;
    int v = (i < n) ? deg[i] : 0;
#pragma unroll
    for (int off = 1; off < 64; off <<= 1) {
      int u = __shfl_up(v, off, 64);
      if (lane >= off) v += u;
    }
    if (lane == 63) wsum[w] = v;
    __syncthreads();
    if (w == 0) {
      int t = (lane < 16) ? wsum[lane] : 0;
#pragma unroll
      for (int off = 1; off < 16; off <<= 1) {
        int u = __shfl_up(t, off, 64);
        if (lane >= off) t += u;
      }
      if (lane < 16) wsum[lane] = t;
    }
    __syncthreads();
    int add = carryS + (w > 0 ? wsum[w - 1] : 0);
    if (i < n) rowstart[i + 1] = v + add;
    __syncthreads();
    if (tid == 0) carryS += wsum[15];
    __syncthreads();
  }
}

__global__ void scatter_kernel(const int* __restrict__ src, const int* __restrict__ dstp,
                               const int* __restrict__ rowstart, int* __restrict__ cursor,
                               int* __restrict__ csr, int n) {
  int i = blockIdx.x * blockDim.x + threadIdx.x;
  if (i < n) {
    int d = dstp[i];
    int pos = atomicAdd(&cursor[d], 1);
    csr[rowstart[d] + pos] = src[i];
  }
}

__global__ void sort_kernel(const int* __restrict__ rowstart, int* __restrict__ csr, int n) {
  int i = blockIdx.x * blockDim.x + threadIdx.x;
  if (i >= n) return;
  int a = rowstart[i], b = rowstart[i + 1];
  for (int j = a + 1; j < b; j++) {
    int v = csr[j];
    int k = j - 1;
    while (k >= a && csr[k] > v) { csr[k + 1] = csr[k]; k--; }
    csr[k + 1] = v;
  }
}

// ---------------- conversions ----------------
__global__ void conv_h_kernel(const float* __restrict__ X, f16* __restrict__ XH, int n4) {
  int i = blockIdx.x * blockDim.x + threadIdx.x;
  if (i < n4) {
    float4 v = *(const float4*)(X + (size_t)i * 4);
    f16x4 o = {(f16)v.x, (f16)v.y, (f16)v.z, (f16)v.w};
    *(f16x4*)(XH + (size_t)i * 4) = o;
  }
}

// all six W [128][HC] f32 -> WT [HC][128] f16, LDS tile transpose
__global__ __launch_bounds__(256) void transconv_all(
    const float* __restrict__ W0, const float* __restrict__ W1,
    const float* __restrict__ W2, const float* __restrict__ W3,
    const float* __restrict__ W4, const float* __restrict__ W5,
    f16* O0, f16* O1, f16* O2, f16* O3, f16* O4, f16* O5) {
  const float* W; f16* O; int HC;
  switch (blockIdx.z) {
    case 0: W = W0; O = O0; HC = 1024; break;
    case 1: W = W1; O = O1; HC = 1024; break;
    case 2: W = W2; O = O2; HC = 1024; break;
    case 3: W = W3; O = O3; HC = 1024; break;
    case 4: W = W4; O = O4; HC = 512; break;
    default: W = W5; O = O5; HC = 512; break;
  }
  int c0 = blockIdx.x * 32;
  if (c0 >= HC) return;
  __shared__ float t[32][33];
  int k0 = blockIdx.y * 32;
  int tx = threadIdx.x & 31, ty = threadIdx.x >> 5;  // 32 x 8
#pragma unroll
  for (int j = 0; j < 4; j++) {
    int k = k0 + ty + j * 8;
    t[ty + j * 8][tx] = W[(size_t)k * HC + c0 + tx];
  }
  __syncthreads();
#pragma unroll
  for (int j = 0; j < 4; j++) {
    int c = c0 + ty + j * 8;
    O[(size_t)c * 128 + k0 + tx] = (f16)t[tx][ty + j * 8];
  }
}

// ---------------- f16 MFMA GEMM: C[M,Nout] = A[M,128] @ BT[Nout,128]^T ----------------
__global__ __launch_bounds__(256) void gemm_f16(const f16* __restrict__ A,
                                                const f16* __restrict__ BT,
                                                f16* __restrict__ C, int M, int Nout) {
  const int w = threadIdx.x >> 6, lane = threadIdx.x & 63;
  const int wm = w >> 1, wn = w & 1;
  const int row0 = blockIdx.x * 128 + wm * 64;
  const int col0 = blockIdx.y * 128 + wn * 64;
  const int lr = lane & 15, lk = (lane >> 4) * 8;

  f32x4 acc[4][4] = {};
  const f16* Arow[4];
  const f16* Brow[4];
#pragma unroll
  for (int m = 0; m < 4; m++) {
    int r = row0 + m * 16 + lr;
    r = r < M ? r : M - 1;
    Arow[m] = A + (size_t)r * 128 + lk;
  }
#pragma unroll
  for (int n = 0; n < 4; n++) {
    int c = col0 + n * 16 + lr;
    Brow[n] = BT + (size_t)c * 128 + lk;
  }
#pragma unroll
  for (int ks = 0; ks < 4; ks++) {
    f16x8 a[4], b[4];
#pragma unroll
    for (int m = 0; m < 4; m++) a[m] = *(const f16x8*)(Arow[m] + ks * 32);
#pragma unroll
    for (int n = 0; n < 4; n++) b[n] = *(const f16x8*)(Brow[n] + ks * 32);
#pragma unroll
    for (int m = 0; m < 4; m++)
#pragma unroll
      for (int n = 0; n < 4; n++)
        acc[m][n] = __builtin_amdgcn_mfma_f32_16x16x32_f16(a[m], b[n], acc[m][n], 0, 0, 0);
  }
#pragma unroll
  for (int m = 0; m < 4; m++) {
    int rbase = row0 + m * 16 + (lane >> 4) * 4;
#pragma unroll
    for (int r = 0; r < 4; r++) {
      int rr = rbase + r;
      if (rr < M) {
#pragma unroll
        for (int n = 0; n < 4; n++) {
          int c = col0 + n * 16 + lr;
          C[(size_t)rr * Nout + c] = (f16)acc[m][n][r];
        }
      }
    }
  }
}

// ---------------- fused GATv2 aggregation (fp16 packed, subgroup-per-dst, unroll 2) ----------------
__device__ __forceinline__ f16x2 pr(f16x8 v, int q) { return f16x2{v[2 * q], v[2 * q + 1]}; }

__device__ __forceinline__ f16x2 leaky2(f16x2 z) {
  f16x2 zs = z * (f16)0.2f;
  return __builtin_elementwise_max(z, zs);
}

template <int H, bool RELU, bool WH>
__global__ __launch_bounds__(H * 64) void agg_kernel(
    const float* __restrict__ h_in, const f16* __restrict__ xlr, int xroff, int stride,
    const float* __restrict__ att, const float* __restrict__ bias,
    const int* __restrict__ csr, const int* __restrict__ rowstart,
    float* __restrict__ h_out, f16* __restrict__ hh) {
  __shared__ float headout[H][4][DH];
  const int h = threadIdx.x >> 6;
  const int lane = threadIdx.x & 63;
  const int g = lane >> 4, u = lane & 15;
  const int c0 = u * 8;
  const int dst = blockIdx.x * 4 + g;

  const f16* xl = xlr + h * DH + c0;       // per-lane base; row = + src*stride
  const f16* xr = xlr + xroff;

  f16x2 att2[4], xr2[4];
  {
    float a0[8];
    const float* ap = att + h * DH + c0;
    *(float4*)a0 = *(const float4*)ap;
    *(float4*)(a0 + 4) = *(const float4*)(ap + 4);
#pragma unroll
    for (int q = 0; q < 4; q++) att2[q] = f16x2{(f16)a0[2 * q], (f16)a0[2 * q + 1]};
    f16x8 xrv = *(const f16x8*)(xr + (size_t)dst * stride + h * DH + c0);
#pragma unroll
    for (int q = 0; q < 4; q++) xr2[q] = pr(xrv, q);
  }

  const int js = rowstart[dst], je = rowstart[dst + 1];

  // self loop seed
  float m, s;
  f16x2 acc[4];
  {
    f16x8 xv = *(const f16x8*)(xl + (size_t)dst * stride);
    float ea = 0.f, eb = 0.f;
#pragma unroll
    for (int q = 0; q < 2; q++) {
      ea = __builtin_amdgcn_fdot2(leaky2(pr(xv, q) + xr2[q]), att2[q], ea, false);
      eb = __builtin_amdgcn_fdot2(leaky2(pr(xv, q + 2) + xr2[q + 2]), att2[q + 2], eb, false);
    }
    float e = ea + eb;
#pragma unroll
    for (int off = 1; off < 16; off <<= 1) e += __shfl_xor(e, off, 64);
    m = e;
    s = 1.f;
#pragma unroll
    for (int q = 0; q < 4; q++) acc[q] = pr(xv, q);
  }

  // 2-deep prefetch
  f16x8 pf0 = {}, pf1 = {};
  if (js < je) pf0 = *(const f16x8*)(xl + (size_t)csr[js] * stride);
  if (js + 1 < je) pf1 = *(const f16x8*)(xl + (size_t)csr[js + 1] * stride);

  int j = js;
  for (; j + 1 < je; j += 2) {
    f16x8 cv0 = pf0, cv1 = pf1;
    int ja = (j + 2 < je) ? j + 2 : je - 1;
    int jb = (j + 3 < je) ? j + 3 : je - 1;
    pf0 = *(const f16x8*)(xl + (size_t)csr[ja] * stride);
    pf1 = *(const f16x8*)(xl + (size_t)csr[jb] * stride);

    float e0a = 0.f, e0b = 0.f, e1a = 0.f, e1b = 0.f;
#pragma unroll
    for (int q = 0; q < 2; q++) {
      e0a = __builtin_amdgcn_fdot2(leaky2(pr(cv0, q) + xr2[q]), att2[q], e0a, false);
      e0b = __builtin_amdgcn_fdot2(leaky2(pr(cv0, q + 2) + xr2[q + 2]), att2[q + 2], e0b, false);
      e1a = __builtin_amdgcn_fdot2(leaky2(pr(cv1, q) + xr2[q]), att2[q], e1a, false);
      e1b = __builtin_amdgcn_fdot2(leaky2(pr(cv1, q + 2) + xr2[q + 2]), att2[q + 2], e1b, false);
    }
    float e0 = e0a + e0b, e1 = e1a + e1b;
#pragma unroll
    for (int off = 1; off < 16; off <<= 1) {
      e0 += __shfl_xor(e0, off, 64);
      e1 += __shfl_xor(e1, off, 64);
    }
    float mn = fmaxf(fmaxf(m, e0), e1);   // v_max3_f32
    float a = __expf(m - mn);
    float p0 = __expf(e0 - mn);
    float p1 = __expf(e1 - mn);
    s = s * a + p0 + p1;
    f16 ah = (f16)a, g0 = (f16)p0, g1 = (f16)p1;
    f16x2 a2 = {ah, ah}, q0 = {g0, g0}, q1 = {g1, g1};
#pragma unroll
    for (int q = 0; q < 4; q++) {
      f16x2 t = acc[q] * a2;
      t = pr(cv0, q) * q0 + t;
      t = pr(cv1, q) * q1 + t;
      acc[q] = t;
    }
    m = mn;
  }
  if (j < je) {  // tail edge
    f16x8 cv = pf0;
    float ea = 0.f, eb = 0.f;
#pragma unroll
    for (int q = 0; q < 2; q++) {
      ea = __builtin_amdgcn_fdot2(leaky2(pr(cv, q) + xr2[q]), att2[q], ea, false);
      eb = __builtin_amdgcn_fdot2(leaky2(pr(cv, q + 2) + xr2[q + 2]), att2[q + 2], eb, false);
    }
    float e = ea + eb;
#pragma unroll
    for (int off = 1; off < 16; off <<= 1) e += __shfl_xor(e, off, 64);
    float mn = fmaxf(m, e);
    float a = __expf(m - mn);
    float p = __expf(e - mn);
    s = s * a + p;
    f16 ah = (f16)a, gh = (f16)p;
    f16x2 a2 = {ah, ah}, p2 = {gh, gh};
#pragma unroll
    for (int q = 0; q < 4; q++) acc[q] = acc[q] * a2 + pr(cv, q) * p2;
    m = mn;
  }

  float inv = 1.f / s;
#pragma unroll
  for (int q = 0; q < 4; q++) {
    headout[h][g][c0 + 2 * q] = (float)acc[q][0] * inv;
    headout[h][g][c0 + 2 * q + 1] = (float)acc[q][1] * inv;
  }
  __syncthreads();
  for (int t = threadIdx.x; t < 4 * DH; t += H * 64) {
    int d = t >> 7, c = t & 127;
    float sum = 0.f;
#pragma unroll
    for (int q = 0; q < H; q++) sum += headout[q][d][c];
    float r = sum * (1.f / H) + bias[c];
    if (RELU) r = fmaxf(r, 0.f);
    int node = blockIdx.x * 4 + d;
    float o = r + h_in[(size_t)node * DH + c];
    h_out[(size_t)node * DH + c] = o;
    if (WH) hh[(size_t)node * DH + c] = (f16)o;
  }
}

extern "C" void kernel_launch(void* const* d_in, const int* in_sizes, int n_in,
                              void* d_out, int out_size, void* d_ws, size_t ws_size,
                              hipStream_t stream) {
  const float* x = (const float*)d_in[0];
  const int* ei = (const int*)d_in[1];
  const float* Wl1 = (const float*)d_in[2];
  const float* Wr1 = (const float*)d_in[3];
  const float* att1 = (const float*)d_in[4];
  const float* b1 = (const float*)d_in[5];
  const float* Wl2 = (const float*)d_in[6];
  const float* Wr2 = (const float*)d_in[7];
  const float* att2 = (const float*)d_in[8];
  const float* b2 = (const float*)d_in[9];
  const float* Wl3 = (const float*)d_in[10];
  const float* Wr3 = (const float*)d_in[11];
  const float* att3 = (const float*)d_in[12];
  const float* b3 = (const float*)d_in[13];
  float* out = (float*)d_out;

  char* p = (char*)d_ws;
  f16* xlr = (f16*)p; p += (size_t)NN * 2048 * 2;
  f16* xh  = (f16*)p; p += (size_t)NN * DH * 2;
  f16* h1h = (f16*)p; p += (size_t)NN * DH * 2;
  f16* h2h = (f16*)p; p += (size_t)NN * DH * 2;
  f16* WT1 = (f16*)p; p += (size_t)2048 * 128 * 2;
  f16* WT2 = (f16*)p; p += (size_t)2048 * 128 * 2;
  f16* WT3 = (f16*)p; p += (size_t)1024 * 128 * 2;
  float* h1 = (float*)p; p += (size_t)NN * DH * 4;
  float* h2 = (float*)p; p += (size_t)NN * DH * 4;
  int* deg      = (int*)p; p += (size_t)NN * 4;
  int* cursor   = (int*)p; p += (size_t)NN * 4;
  int* rowstart = (int*)p; p += (size_t)(NN + 1) * 4;
  int* csr      = (int*)p;

  const int* esrc = ei;
  const int* edst = ei + NE;

  hipMemsetAsync(deg, 0, sizeof(int) * 2 * NN, stream);  // deg + cursor
  count_kernel<<<(NE + 255) / 256, 256, 0, stream>>>(edst, deg, NE);
  scan_all<<<1, 1024, 0, stream>>>(deg, rowstart, NN);
  scatter_kernel<<<(NE + 255) / 256, 256, 0, stream>>>(esrc, edst, rowstart, cursor, csr, NE);
  sort_kernel<<<(NN + 255) / 256, 256, 0, stream>>>(rowstart, csr, NN);

  // conversions (2 launches)
  conv_h_kernel<<<(NN * DH / 4 + 255) / 256, 256, 0, stream>>>(x, xh, NN * DH / 4);
  transconv_all<<<dim3(32, 4, 6), 256, 0, stream>>>(
      Wl1, Wr1, Wl2, Wr2, Wl3, Wr3,
      WT1, WT1 + (size_t)1024 * 128, WT2, WT2 + (size_t)1024 * 128,
      WT3, WT3 + (size_t)512 * 128);

  dim3 gA((NN + 127) / 128, 16);
  dim3 gB((NN + 127) / 128, 8);
  const int nblk = NN / 4;  // 5000

  // layer 1
  gemm_f16<<<gA, 256, 0, stream>>>(xh, WT1, xlr, NN, 2048);
  agg_kernel<8, true, true><<<nblk, 512, 0, stream>>>(x, xlr, 1024, 2048, att1, b1, csr, rowstart, h1, h1h);
  // layer 2
  gemm_f16<<<gA, 256, 0, stream>>>(h1h, WT2, xlr, NN, 2048);
  agg_kernel<8, true, true><<<nblk, 512, 0, stream>>>(h1, xlr, 1024, 2048, att2, b2, csr, rowstart, h2, h2h);
  // layer 3
  gemm_f16<<<gB, 256, 0, stream>>>(h2h, WT3, xlr, NN, 1024);
  agg_kernel<4, false, false><<<nblk, 256, 0, stream>>>(h2, xlr, 512, 1024, att3, b3, csr, rowstart, out, nullptr);
}